// Round 7
// baseline (3767.267 us; speedup 1.0000x reference)
//
#include <hip/hip_runtime.h>
#include <stdint.h>
#include <math.h>

#define NB 4
#define CIN 512
#define CMID 512
#define HH 50
#define WW 50
#define NPIX 2500
#define AA 9
#define RR 22500
#define PB 6000
#define PA 300
#define LOCCH 36
#define SCORECH 18
#define HEADCH 54
#define CI_T 8

typedef unsigned long long u64;

// ---------------- anchors ----------------
__global__ void anchor_kernel(float* __restrict__ out4) {
    int r = blockIdx.x * 256 + threadIdx.x;
    if (r >= RR) return;
    int a = r % AA;
    int p = r / AA;
    int gy = p / WW, gx = p % WW;
    int ri = a / 3, si = a % 3;
    const double ratios[3] = {0.5, 1.0, 2.0};
    const double scales[3] = {8.0, 16.0, 32.0};
    double h = 16.0 * sqrt(ratios[ri]) * scales[si];
    double w = 16.0 * sqrt(1.0 / ratios[ri]) * scales[si];
    float by1 = (float)(8.0 - h * 0.5);
    float bx1 = (float)(8.0 - w * 0.5);
    float by2 = (float)(8.0 + h * 0.5);
    float bx2 = (float)(8.0 + w * 0.5);
    float sy = (float)(gy * 16), sx = (float)(gx * 16);
    float* o = out4 + (size_t)r * 4;
    o[0] = by1 + sy; o[1] = bx1 + sx; o[2] = by2 + sy; o[3] = bx2 + sx;
}

// ---------------- 3x3 conv + bias + relu, f64 accumulate ----------------
// v5 = v3 geometry (64co x 8x8px, 4co x 4col/thread, CI_T=8, 26KB LDS)
//    + async-STAGE split: next chunk's global loads issued before compute,
//      written to LDS after the barrier. FMA order identical to v3.
__global__ __launch_bounds__(256) void conv3_f64_v5(
    const float* __restrict__ x, const float* __restrict__ w1,
    const float* __restrict__ b1, double* __restrict__ inter, int nbase) {
    __shared__ __align__(16) double xs[CI_T * 100];       // [ci][row][col] flat, 6400 B
    __shared__ __align__(16) float wsf[CI_T * 9 * 68];    // [q][m] pitch 68, 19584 B

    int tile = blockIdx.x;
    int ty = tile / 7, tx = tile % 7;
    int co0 = blockIdx.y * 64;
    int bz = blockIdx.z;
    int n = nbase + bz;
    int tid = threadIdx.x;
    int tm = tid & 15;            // cout-quad id
    int tp = tid >> 4;            // pixel-quad id
    int pyt = tp >> 1;            // row 0..7
    int px0 = (tp & 1) * 4;       // col 0 or 4
    int gy0 = ty * 8, gx0 = tx * 8;
    const float* xb = x + (size_t)n * CIN * NPIX;
    double* ib = inter + (size_t)bz * CMID * NPIX;

    // precompute x staging indices (4 slots; slot k valid iff tid + k*256 < 800)
    int xg[4];
    #pragma unroll
    for (int k = 0; k < 4; ++k) {
        int e = tid + k * 256;
        if (e < CI_T * 100) {
            int ci = e / 100, rc = e % 100;
            int row = rc / 10, col = rc % 10;
            int gy = gy0 - 1 + row, gx = gx0 - 1 + col;
            xg[k] = (gy >= 0 && gy < HH && gx >= 0 && gx < WW)
                        ? (ci * NPIX + gy * WW + gx) : -1;
        } else {
            xg[k] = -1;
        }
    }
    int mm0 = tid / 72;
    int qq0 = tid - mm0 * 72;

    double acc[4][4] = {};

    // ---- prologue: stage chunk 0 directly
    #pragma unroll
    for (int k = 0; k < 4; ++k) {
        int e = tid + k * 256;
        if (e < CI_T * 100) {
            float v = (xg[k] >= 0) ? xb[xg[k]] : 0.f;
            xs[e] = (double)v;
        }
    }
    {
        int mm = mm0, qq = qq0;
        #pragma unroll
        for (int k = 0; k < 18; ++k) {
            wsf[qq * 68 + mm] = w1[(size_t)(co0 + mm) * (CIN * 9) + qq];
            qq += 40; mm += 3; if (qq >= 72) { qq -= 72; mm += 1; }
        }
    }
    __syncthreads();

    for (int cc = 0; cc < CIN; cc += CI_T) {
        int cn = cc + CI_T;
        bool pf = cn < CIN;
        float xr[4], wr[18];
        // ---- issue next-chunk global loads (in flight during compute)
        if (pf) {
            #pragma unroll
            for (int k = 0; k < 4; ++k) {
                int e = tid + k * 256;
                if (e < CI_T * 100)
                    xr[k] = (xg[k] >= 0) ? xb[(size_t)cn * NPIX + xg[k]] : 0.f;
            }
            int mm = mm0, qq = qq0;
            #pragma unroll
            for (int k = 0; k < 18; ++k) {
                wr[k] = w1[(size_t)(co0 + mm) * (CIN * 9) + (size_t)cn * 9 + qq];
                qq += 40; mm += 3; if (qq >= 72) { qq -= 72; mm += 1; }
            }
        }

        // ---- compute current chunk from LDS (identical to v3)
        for (int ci = 0; ci < CI_T; ++ci) {
            #pragma unroll
            for (int ky = 0; ky < 3; ++ky) {
                double xa[6];
                const double* xrow = &xs[ci * 100 + (pyt + ky) * 10 + px0];
                *(double2*)&xa[0] = *(const double2*)&xrow[0];
                *(double2*)&xa[2] = *(const double2*)&xrow[2];
                *(double2*)&xa[4] = *(const double2*)&xrow[4];
                #pragma unroll
                for (int kx = 0; kx < 3; ++kx) {
                    float4 wf = *(const float4*)&wsf[(ci * 9 + ky * 3 + kx) * 68 + tm * 4];
                    double w0 = (double)wf.x, w1v = (double)wf.y;
                    double w2 = (double)wf.z, w3 = (double)wf.w;
                    #pragma unroll
                    for (int j = 0; j < 4; ++j) {
                        double xv = xa[kx + j];
                        acc[0][j] = fma(w0, xv, acc[0][j]);
                        acc[1][j] = fma(w1v, xv, acc[1][j]);
                        acc[2][j] = fma(w2, xv, acc[2][j]);
                        acc[3][j] = fma(w3, xv, acc[3][j]);
                    }
                }
            }
        }
        __syncthreads();

        // ---- write staged regs -> LDS
        if (pf) {
            #pragma unroll
            for (int k = 0; k < 4; ++k) {
                int e = tid + k * 256;
                if (e < CI_T * 100) xs[e] = (double)xr[k];
            }
            int mm = mm0, qq = qq0;
            #pragma unroll
            for (int k = 0; k < 18; ++k) {
                wsf[qq * 68 + mm] = wr[k];
                qq += 40; mm += 3; if (qq >= 72) { qq -= 72; mm += 1; }
            }
            __syncthreads();
        }
    }

    int gy = gy0 + pyt;
    #pragma unroll
    for (int i = 0; i < 4; ++i) {
        int co = co0 + tm * 4 + i;
        double bias = (double)b1[co];
        #pragma unroll
        for (int j = 0; j < 4; ++j) {
            int gx = gx0 + px0 + j;
            if (gy < HH && gx < WW) {
                double v = fmax(acc[i][j] + bias, 0.0);
                ib[(size_t)co * NPIX + gy * WW + gx] = v;
            }
        }
    }
}

// ---------------- 1x1 heads, f64: block 256, 64px x 4 o-groups ----------------
#define HP 64
#define HCI 32
__global__ __launch_bounds__(256) void heads_kernel_f64_v2(
    const double* __restrict__ inter,
    const float* __restrict__ w_loc, const float* __restrict__ b_loc,
    const float* __restrict__ w_score, const float* __restrict__ b_score,
    double* __restrict__ loc64, double* __restrict__ score64,
    float* __restrict__ out_loc, float* __restrict__ out_score, int nbase) {
    __shared__ double xsh[HCI][HP];
    __shared__ double wsh[HEADCH][HCI];
    int bz = blockIdx.y;
    int n = nbase + bz;
    const double* ib = inter + (size_t)bz * CMID * NPIX;
    int p0 = blockIdx.x * HP;
    int tid = threadIdx.x;
    int pl = tid & 63;
    int g = tid >> 6;          // 0..3
    int u0 = g * 14;           // g=3 covers u 42..53 (12 outs)
    double acc[14] = {};

    for (int cc = 0; cc < CMID; cc += HCI) {
        for (int e = tid; e < HCI * HP; e += 256) {
            int ci = e >> 6, p = e & 63;
            int gp = p0 + p;
            xsh[ci][p] = (gp < NPIX) ? ib[(size_t)(cc + ci) * NPIX + gp] : 0.0;
        }
        for (int e = tid; e < HEADCH * HCI; e += 256) {
            int ci = e & 31, u = e >> 5;
            float wv = (u < LOCCH) ? w_loc[(size_t)u * CMID + cc + ci]
                                   : w_score[(size_t)(u - LOCCH) * CMID + cc + ci];
            wsh[u][ci] = (double)wv;
        }
        __syncthreads();
        for (int ci = 0; ci < HCI; ++ci) {
            double xv = xsh[ci][pl];
            #pragma unroll
            for (int o = 0; o < 14; ++o) {
                int u = u0 + o;
                if (u < HEADCH) acc[o] = fma(wsh[u][ci], xv, acc[o]);
            }
        }
        __syncthreads();
    }

    int gp = p0 + pl;
    if (gp < NPIX) {
        #pragma unroll
        for (int o = 0; o < 14; ++o) {
            int u = u0 + o;
            if (u < HEADCH) {
                if (u < LOCCH) {
                    double v = acc[o] + (double)b_loc[u];
                    loc64[(size_t)n * RR * 4 + (size_t)gp * 36 + u] = v;
                    out_loc[(size_t)n * RR * 4 + (size_t)gp * 36 + u] = (float)v;
                } else {
                    int us = u - LOCCH;
                    double v = acc[o] + (double)b_score[us];
                    score64[(size_t)n * RR * 2 + (size_t)gp * 18 + us] = v;
                    out_score[(size_t)n * RR * 2 + (size_t)gp * 18 + us] = (float)v;
                }
            }
        }
    }
}

// ---------------- decode boxes + softmax-fg + keys, f64 ----------------
__global__ void box_kernel_f64(const double* __restrict__ loc64,
                               const double* __restrict__ score64,
                               const float* __restrict__ anchor,
                               const int* __restrict__ imh_p, const int* __restrict__ imw_p,
                               double* __restrict__ boxes, u64* __restrict__ keys) {
    int idx = blockIdx.x * 256 + threadIdx.x;
    if (idx >= NB * RR) return;
    int r = idx % RR;
    const double* l = loc64 + (size_t)idx * 4;
    double a0 = (double)anchor[(size_t)r * 4 + 0];
    double a1 = (double)anchor[(size_t)r * 4 + 1];
    double a2 = (double)anchor[(size_t)r * 4 + 2];
    double a3 = (double)anchor[(size_t)r * 4 + 3];
    double ah = a2 - a0, aw = a3 - a1;
    double acy = a0 + 0.5 * ah, acx = a1 + 0.5 * aw;
    double cy = l[0] * ah + acy, cx = l[1] * aw + acx;
    double h = exp(l[2]) * ah, w = exp(l[3]) * aw;
    double imh = (double)imh_p[0], imw = (double)imw_p[0];
    double y1 = fmin(fmax(cy - 0.5 * h, 0.0), imh);
    double x1 = fmin(fmax(cx - 0.5 * w, 0.0), imw);
    double y2 = fmin(fmax(cy + 0.5 * h, 0.0), imh);
    double x2 = fmin(fmax(cx + 0.5 * w, 0.0), imw);
    bool valid = ((y2 - y1) >= 16.0) && ((x2 - x1) >= 16.0);
    double* b = boxes + (size_t)idx * 4;
    b[0] = y1; b[1] = x1; b[2] = y2; b[3] = x2;
    double s0 = score64[(size_t)idx * 2];
    double s1 = score64[(size_t)idx * 2 + 1];
    double m = fmax(s0, s1);
    double e0 = exp(s0 - m), e1 = exp(s1 - m);
    double sc = valid ? (e1 / (e0 + e1)) : -__builtin_inf();
    u64 bits = (u64)__double_as_longlong(sc);
    u64 t = (bits >> 63) ? ~bits : (bits | 0x8000000000000000ull);
    keys[idx] = (t & 0xFFFFFFFFFFFF8000ull) | (u64)(32767 - r);
}

// ---------------- top-6000 select + full sort (per batch) ----------------
__global__ __launch_bounds__(1024) void select_kernel(
    const u64* __restrict__ keys, const double* __restrict__ boxes,
    double* __restrict__ sbox, int* __restrict__ sval) {
    __shared__ unsigned int hist[256];
    __shared__ u64 cand[8192];
    __shared__ unsigned int s_sel, s_base, s_cnt;
    int n = blockIdx.x;
    int tid = threadIdx.x;
    const u64* k = keys + (size_t)n * RR;

    u64 prefix = 0;
    unsigned int base = 0;
    for (int round = 0; round < 3; ++round) {
        if (tid < 256) hist[tid] = 0;
        __syncthreads();
        int shift_match = 64 - 8 * round;
        int shift_bin = 56 - 8 * round;
        for (int r = tid; r < RR; r += 1024) {
            u64 kv = k[r];
            bool match = (round == 0) || ((kv >> shift_match) == prefix);
            if (match) atomicAdd(&hist[(unsigned int)((kv >> shift_bin) & 0xFF)], 1u);
        }
        __syncthreads();
        if (tid == 0) {
            unsigned int c = base;
            int sel = 0;
            for (int v = 255; v >= 0; --v) {
                if (c + hist[v] >= PB) { sel = v; break; }
                c += hist[v];
            }
            s_sel = (unsigned int)sel;
            s_base = c;
        }
        __syncthreads();
        prefix = (prefix << 8) | (u64)s_sel;
        base = s_base;
        __syncthreads();
    }

    if (tid == 0) s_cnt = 0;
    __syncthreads();
    for (int r = tid; r < RR; r += 1024) {
        u64 kv = k[r];
        if ((kv >> 40) >= prefix) {
            unsigned int pos = atomicAdd(&s_cnt, 1u);
            if (pos < 8192u) cand[pos] = kv;
        }
    }
    __syncthreads();
    unsigned int cnt = s_cnt;
    if (cnt > 8192u) cnt = 8192u;
    for (unsigned int i = cnt + tid; i < 8192u; i += 1024u) cand[i] = 0ull;
    __syncthreads();

    for (unsigned int kk = 2; kk <= 8192; kk <<= 1) {
        for (unsigned int j = kk >> 1; j > 0; j >>= 1) {
            for (unsigned int t = tid; t < 4096; t += 1024) {
                unsigned int i = ((t & ~(j - 1)) << 1) | (t & (j - 1));
                unsigned int l = i | j;
                u64 a = cand[i], b = cand[l];
                bool desc = ((i & kk) == 0);
                if ((a < b) == desc) { cand[i] = b; cand[l] = a; }
            }
            __syncthreads();
        }
    }

    for (int s = tid; s < PB; s += 1024) {
        u64 kv = cand[s];
        int valid = (int)(kv >> 63);
        double b0 = 0.0, b1 = 0.0, b2 = 0.0, b3 = 0.0;
        if (valid) {
            int r = 32767 - (int)(kv & 0x7FFFull);
            const double* bp = boxes + ((size_t)n * RR + r) * 4;
            b0 = bp[0]; b1 = bp[1]; b2 = bp[2]; b3 = bp[3];
        }
        double* sp = sbox + ((size_t)n * PB + s) * 4;
        sp[0] = b0; sp[1] = b1; sp[2] = b2; sp[3] = b3;
        sval[n * PB + s] = valid;
    }
}

// ---------------- greedy NMS, word-scan over keep bitmask ----------------
__global__ __launch_bounds__(1024) void nms_kernel_f64_v2(
    const double* __restrict__ sbox, const int* __restrict__ sval,
    float* __restrict__ rois, float* __restrict__ rind) {
    __shared__ unsigned int keepw[188];   // 188*32 = 6016 >= 6000
    __shared__ double bi[4];
    int n = blockIdx.x;
    int tid = threadIdx.x;

    double by1[6], bx1[6], by2[6], bx2[6];
    bool kp[6];
    if (tid < 188) keepw[tid] = 0u;
    __syncthreads();
    #pragma unroll
    for (int c = 0; c < 6; ++c) {
        int j = tid + c * 1024;
        bool v = false;
        double a0 = 0, a1 = 0, a2 = 0, a3 = 0;
        if (j < PB) {
            const double* bp = sbox + ((size_t)n * PB + j) * 4;
            a0 = bp[0]; a1 = bp[1]; a2 = bp[2]; a3 = bp[3];
            v = sval[n * PB + j] != 0;
        }
        by1[c] = a0; bx1[c] = a1; by2[c] = a2; bx2[c] = a3;
        kp[c] = v;
        if (v) atomicOr(&keepw[j >> 5], 1u << (j & 31));
    }
    __syncthreads();

    int kc = 0;
    for (int wi = 0; wi < 188 && kc < PA; ++wi) {
        unsigned int word = keepw[wi];
        while (word) {
            int b = __ffs(word) - 1;
            int i = (wi << 5) + b;
            int owner = i & 1023;
            int slot = i >> 10;
            if (tid == owner) {
                float* rp = rois + ((size_t)n * PA + kc) * 4;
                rp[0] = (float)by1[slot]; rp[1] = (float)bx1[slot];
                rp[2] = (float)by2[slot]; rp[3] = (float)bx2[slot];
                bi[0] = by1[slot]; bi[1] = bx1[slot];
                bi[2] = by2[slot]; bi[3] = bx2[slot];
            }
            ++kc;
            if (kc >= PA) break;
            __syncthreads();
            double yi1 = bi[0], xi1 = bi[1], yi2 = bi[2], xi2 = bi[3];
            double ai = (yi2 - yi1) * (xi2 - xi1);
            #pragma unroll
            for (int c = 0; c < 6; ++c) {
                int j = tid + c * 1024;
                if (j > i && kp[c]) {
                    double ty = fmax(yi1, by1[c]);
                    double tx = fmax(xi1, bx1[c]);
                    double byy = fmin(yi2, by2[c]);
                    double bxx = fmin(xi2, bx2[c]);
                    double ih = fmax(byy - ty, 0.0);
                    double iw = fmax(bxx - tx, 0.0);
                    double inter = ih * iw;
                    double aj = (by2[c] - by1[c]) * (bx2[c] - bx1[c]);
                    double iou = inter / (ai + aj - inter + 1e-9);
                    if (iou > 0.7) {
                        kp[c] = false;
                        atomicAnd(&keepw[j >> 5], ~(1u << (j & 31)));
                    }
                }
            }
            __syncthreads();
            unsigned int clear = (b >= 31) ? 0u : (0xFFFFFFFFu << (b + 1));
            word = keepw[wi] & clear;
        }
    }
    __syncthreads();

    for (int p = kc + tid; p < PA; p += 1024) {
        float* rp = rois + ((size_t)n * PA + p) * 4;
        rp[0] = 0.f; rp[1] = 0.f; rp[2] = 0.f; rp[3] = 0.f;
    }
    for (int p = tid; p < PA; p += 1024)
        rind[n * PA + p] = (float)n;
}

// ---------------- launch ----------------
extern "C" void kernel_launch(void* const* d_in, const int* in_sizes, int n_in,
                              void* d_out, int out_size, void* d_ws, size_t ws_size,
                              hipStream_t stream) {
    const float* x = (const float*)d_in[0];
    const float* w1 = (const float*)d_in[1];
    const float* b1 = (const float*)d_in[2];
    const float* w_score = (const float*)d_in[3];
    const float* b_score = (const float*)d_in[4];
    const float* w_loc = (const float*)d_in[5];
    const float* b_loc = (const float*)d_in[6];
    const int* img_h = (const int*)d_in[7];
    const int* img_w = (const int*)d_in[8];

    float* out = (float*)d_out;
    float* out_loc = out;
    float* out_score = out + 360000;
    float* out_rois = out + 540000;
    float* out_rind = out + 544800;
    float* out_anchor = out + 546000;

    const size_t interB_batched = (size_t)NB * CMID * NPIX * 8;
    const size_t interB_serial = (size_t)CMID * NPIX * 8;
    const size_t restB = 2880000 + 1440000 + 2880000 + 720000 + 768000 + 96000;
    bool batched = ws_size >= interB_batched + restB;

    char* p = (char*)d_ws;
    double* inter64 = (double*)p; p += batched ? interB_batched : interB_serial;
    double* loc64   = (double*)p; p += 2880000;
    double* score64 = (double*)p; p += 1440000;
    double* boxes64 = (double*)p; p += 2880000;
    u64*    keys    = (u64*)p;    p += 720000;
    double* sbox64  = (double*)p; p += 768000;
    int*    sval    = (int*)p;

    hipLaunchKernelGGL(anchor_kernel, dim3(88), dim3(256), 0, stream, out_anchor);
    if (batched) {
        hipLaunchKernelGGL(conv3_f64_v5, dim3(49, 8, NB), dim3(256), 0, stream,
                           x, w1, b1, inter64, 0);
        hipLaunchKernelGGL(heads_kernel_f64_v2, dim3(40, NB), dim3(256), 0, stream,
                           inter64, w_loc, b_loc, w_score, b_score,
                           loc64, score64, out_loc, out_score, 0);
    } else {
        for (int n = 0; n < NB; ++n) {
            hipLaunchKernelGGL(conv3_f64_v5, dim3(49, 8, 1), dim3(256), 0, stream,
                               x, w1, b1, inter64, n);
            hipLaunchKernelGGL(heads_kernel_f64_v2, dim3(40, 1), dim3(256), 0, stream,
                               inter64, w_loc, b_loc, w_score, b_score,
                               loc64, score64, out_loc, out_score, n);
        }
    }
    hipLaunchKernelGGL(box_kernel_f64, dim3((NB * RR + 255) / 256), dim3(256), 0, stream,
                       loc64, score64, out_anchor, img_h, img_w, boxes64, keys);
    hipLaunchKernelGGL(select_kernel, dim3(4), dim3(1024), 0, stream, keys, boxes64, sbox64, sval);
    hipLaunchKernelGGL(nms_kernel_f64_v2, dim3(4), dim3(1024), 0, stream, sbox64, sval, out_rois, out_rind);
}

// Round 8
// 2495.389 us; speedup vs baseline: 1.5097x; 1.5097x over previous
//
#include <hip/hip_runtime.h>
#include <stdint.h>
#include <math.h>

#define NB 4
#define CIN 512
#define CMID 512
#define HH 50
#define WW 50
#define NPIX 2500
#define AA 9
#define RR 22500
#define PB 6000
#define PA 300
#define LOCCH 36
#define SCORECH 18
#define HEADCH 54
#define CI_T 8
#define CI_T2 4

typedef unsigned long long u64;

// ---------------- anchors ----------------
__global__ void anchor_kernel(float* __restrict__ out4) {
    int r = blockIdx.x * 256 + threadIdx.x;
    if (r >= RR) return;
    int a = r % AA;
    int p = r / AA;
    int gy = p / WW, gx = p % WW;
    int ri = a / 3, si = a % 3;
    const double ratios[3] = {0.5, 1.0, 2.0};
    const double scales[3] = {8.0, 16.0, 32.0};
    double h = 16.0 * sqrt(ratios[ri]) * scales[si];
    double w = 16.0 * sqrt(1.0 / ratios[ri]) * scales[si];
    float by1 = (float)(8.0 - h * 0.5);
    float bx1 = (float)(8.0 - w * 0.5);
    float by2 = (float)(8.0 + h * 0.5);
    float bx2 = (float)(8.0 + w * 0.5);
    float sy = (float)(gy * 16), sx = (float)(gx * 16);
    float* o = out4 + (size_t)r * 4;
    o[0] = by1 + sy; o[1] = bx1 + sx; o[2] = by2 + sy; o[3] = bx2 + sx;
}

// ---------------- conv v6: split-K=2, 128co x 8x8px, 4co x 8col/thread ----------------
// grid (49, 4cog*2k, nb), block 256. CI_T2=4 -> LDS 22.2KB. Writes f64 partials.
__global__ __launch_bounds__(256) void conv3_f64_v6(
    const float* __restrict__ x, const float* __restrict__ w1,
    double* __restrict__ part) {
    __shared__ __align__(16) double xs[CI_T2 * 100];        // 3200 B
    __shared__ __align__(16) float wsf[CI_T2 * 9 * 132];    // 19008 B

    int tile = blockIdx.x;
    int ty = tile / 7, tx = tile % 7;
    int yy = blockIdx.y;
    int co0 = (yy & 3) * 128;
    int kk = yy >> 2;              // K-half 0/1
    int bz = blockIdx.z;
    int tid = threadIdx.x;
    int tm = tid & 31;             // cout-quad id (co = co0 + tm*4 + i)
    int pyt = tid >> 5;            // pixel row 0..7
    int gy0 = ty * 8, gx0 = tx * 8;
    const float* xb = x + (size_t)bz * CIN * NPIX;
    int cc0 = kk * 256;

    double acc[4][8] = {};

    for (int cc = cc0; cc < cc0 + 256; cc += CI_T2) {
        // stage x (4ci x 10x10 halo), convert once
        for (int e = tid; e < CI_T2 * 100; e += 256) {
            int ci = e / 100, rc = e % 100;
            int row = rc / 10, col = rc % 10;
            int gy = gy0 - 1 + row, gx = gx0 - 1 + col;
            float v = 0.f;
            if (gy >= 0 && gy < HH && gx >= 0 && gx < WW)
                v = xb[(size_t)(cc + ci) * NPIX + gy * WW + gx];
            xs[e] = (double)v;
        }
        // stage weights f32 (128co x 36q), coalesced per-co runs
        for (int e = tid; e < 128 * 36; e += 256) {
            int m = e / 36, q = e % 36;
            wsf[q * 132 + m] = w1[(size_t)(co0 + m) * (CIN * 9) + (size_t)cc * 9 + q];
        }
        __syncthreads();

        for (int ci = 0; ci < CI_T2; ++ci) {
            #pragma unroll
            for (int ky = 0; ky < 3; ++ky) {
                double xa[10];
                const double* xr = &xs[ci * 100 + (pyt + ky) * 10];
                #pragma unroll
                for (int t = 0; t < 5; ++t)
                    *(double2*)&xa[2 * t] = *(const double2*)&xr[2 * t];
                #pragma unroll
                for (int kx = 0; kx < 3; ++kx) {
                    float4 wf = *(const float4*)&wsf[(ci * 9 + ky * 3 + kx) * 132 + tm * 4];
                    double w0 = (double)wf.x, w1v = (double)wf.y;
                    double w2 = (double)wf.z, w3 = (double)wf.w;
                    #pragma unroll
                    for (int j = 0; j < 8; ++j) {
                        double xv = xa[kx + j];
                        acc[0][j] = fma(w0, xv, acc[0][j]);
                        acc[1][j] = fma(w1v, xv, acc[1][j]);
                        acc[2][j] = fma(w2, xv, acc[2][j]);
                        acc[3][j] = fma(w3, xv, acc[3][j]);
                    }
                }
            }
        }
        __syncthreads();
    }

    int gy = gy0 + pyt;
    if (gy < HH) {
        double* pb = part + (size_t)kk * NB * CMID * NPIX + (size_t)bz * CMID * NPIX;
        #pragma unroll
        for (int i = 0; i < 4; ++i) {
            int co = co0 + tm * 4 + i;
            #pragma unroll
            for (int j = 0; j < 8; ++j) {
                int gx = gx0 + j;
                if (gx < WW)
                    pb[(size_t)co * NPIX + gy * WW + gx] = acc[i][j];
            }
        }
    }
}

// ---------------- reduce partials + bias + relu (in-place into part[0]) --------
__global__ void reduce_bias_relu(const double* __restrict__ part,
                                 const float* __restrict__ b1,
                                 double* __restrict__ inter) {
    size_t idx = (size_t)blockIdx.x * 256 + threadIdx.x;
    const size_t total = (size_t)NB * CMID * NPIX;
    if (idx >= total) return;
    int co = (int)((idx / NPIX) % CMID);
    double v = part[idx] + part[idx + total] + (double)b1[co];
    inter[idx] = fmax(v, 0.0);
}

// ---------------- fallback conv (R5's v3, bit-verified) ----------------
__global__ __launch_bounds__(256) void conv3_f64_v3(
    const float* __restrict__ x, const float* __restrict__ w1,
    const float* __restrict__ b1, double* __restrict__ inter, int nbase) {
    __shared__ __align__(16) double xs[CI_T][10][10];
    __shared__ __align__(16) float wsf[CI_T * 9][68];

    int tile = blockIdx.x;
    int ty = tile / 7, tx = tile % 7;
    int co0 = blockIdx.y * 64;
    int bz = blockIdx.z;
    int n = nbase + bz;
    int tid = threadIdx.x;
    int tm = tid & 15;
    int tp = tid >> 4;
    int pyt = tp >> 1;
    int px0 = (tp & 1) * 4;
    int gy0 = ty * 8, gx0 = tx * 8;
    const float* xb = x + (size_t)n * CIN * NPIX;
    double* ib = inter + (size_t)bz * CMID * NPIX;

    double acc[4][4] = {};

    for (int cc = 0; cc < CIN; cc += CI_T) {
        for (int e = tid; e < CI_T * 100; e += 256) {
            int ci = e / 100, rc = e % 100;
            int row = rc / 10, col = rc % 10;
            int gy = gy0 - 1 + row, gx = gx0 - 1 + col;
            float v = 0.f;
            if (gy >= 0 && gy < HH && gx >= 0 && gx < WW)
                v = xb[(size_t)(cc + ci) * NPIX + gy * WW + gx];
            xs[ci][row][col] = (double)v;
        }
        for (int e = tid; e < 64 * 72; e += 256) {
            int m = e / 72, q = e % 72;
            wsf[q][m] = w1[((size_t)(co0 + m) * CIN + cc) * 9 + q];
        }
        __syncthreads();

        for (int ci = 0; ci < CI_T; ++ci) {
            #pragma unroll
            for (int ky = 0; ky < 3; ++ky) {
                double xa[6];
                const double* xrow = &xs[ci][pyt + ky][px0];
                *(double2*)&xa[0] = *(const double2*)&xrow[0];
                *(double2*)&xa[2] = *(const double2*)&xrow[2];
                *(double2*)&xa[4] = *(const double2*)&xrow[4];
                #pragma unroll
                for (int kx = 0; kx < 3; ++kx) {
                    float4 wf = *(const float4*)&wsf[ci * 9 + ky * 3 + kx][tm * 4];
                    double w0 = (double)wf.x, w1v = (double)wf.y;
                    double w2 = (double)wf.z, w3 = (double)wf.w;
                    #pragma unroll
                    for (int j = 0; j < 4; ++j) {
                        double xv = xa[kx + j];
                        acc[0][j] = fma(w0, xv, acc[0][j]);
                        acc[1][j] = fma(w1v, xv, acc[1][j]);
                        acc[2][j] = fma(w2, xv, acc[2][j]);
                        acc[3][j] = fma(w3, xv, acc[3][j]);
                    }
                }
            }
        }
        __syncthreads();
    }

    int gy = gy0 + pyt;
    #pragma unroll
    for (int i = 0; i < 4; ++i) {
        int co = co0 + tm * 4 + i;
        double bias = (double)b1[co];
        #pragma unroll
        for (int j = 0; j < 4; ++j) {
            int gx = gx0 + px0 + j;
            if (gy < HH && gx < WW) {
                double v = fmax(acc[i][j] + bias, 0.0);
                ib[(size_t)co * NPIX + gy * WW + gx] = v;
            }
        }
    }
}

// ---------------- 1x1 heads, f64 (R5 version) ----------------
#define HP 64
#define HCI 32
__global__ __launch_bounds__(128) void heads_kernel_f64(
    const double* __restrict__ inter,
    const float* __restrict__ w_loc, const float* __restrict__ b_loc,
    const float* __restrict__ w_score, const float* __restrict__ b_score,
    double* __restrict__ loc64, double* __restrict__ score64,
    float* __restrict__ out_loc, float* __restrict__ out_score, int nbase) {
    __shared__ double xsh[HCI][HP];
    __shared__ double wsh[HEADCH][HCI];
    int bz = blockIdx.y;
    int n = nbase + bz;
    const double* ib = inter + (size_t)bz * CMID * NPIX;
    int p0 = blockIdx.x * HP;
    int tid = threadIdx.x;
    int pl = tid & 63;
    int g = tid >> 6;     // 0..1, 27 channels each
    double acc[27] = {};

    for (int cc = 0; cc < CMID; cc += HCI) {
        for (int e = tid; e < HCI * HP; e += 128) {
            int p = e % HP;
            int ci = e / HP;
            int gp = p0 + p;
            xsh[ci][p] = (gp < NPIX) ? ib[(size_t)(cc + ci) * NPIX + gp] : 0.0;
        }
        for (int e = tid; e < HEADCH * HCI; e += 128) {
            int ci = e % HCI;
            int u = e / HCI;
            float wv = (u < LOCCH) ? w_loc[(size_t)u * CMID + cc + ci]
                                   : w_score[(size_t)(u - LOCCH) * CMID + cc + ci];
            wsh[u][ci] = (double)wv;
        }
        __syncthreads();
        for (int ci = 0; ci < HCI; ++ci) {
            double xv = xsh[ci][pl];
            #pragma unroll
            for (int o = 0; o < 27; ++o)
                acc[o] = fma(wsh[g * 27 + o][ci], xv, acc[o]);
        }
        __syncthreads();
    }

    int gp = p0 + pl;
    if (gp < NPIX) {
        #pragma unroll
        for (int o = 0; o < 27; ++o) {
            int u = g * 27 + o;
            if (u < LOCCH) {
                double v = acc[o] + (double)b_loc[u];
                loc64[(size_t)n * RR * 4 + (size_t)gp * 36 + u] = v;
                out_loc[(size_t)n * RR * 4 + (size_t)gp * 36 + u] = (float)v;
            } else {
                int us = u - LOCCH;
                double v = acc[o] + (double)b_score[us];
                score64[(size_t)n * RR * 2 + (size_t)gp * 18 + us] = v;
                out_score[(size_t)n * RR * 2 + (size_t)gp * 18 + us] = (float)v;
            }
        }
    }
}

// ---------------- decode boxes + softmax-fg + keys, f64 ----------------
__global__ void box_kernel_f64(const double* __restrict__ loc64,
                               const double* __restrict__ score64,
                               const float* __restrict__ anchor,
                               const int* __restrict__ imh_p, const int* __restrict__ imw_p,
                               double* __restrict__ boxes, u64* __restrict__ keys) {
    int idx = blockIdx.x * 256 + threadIdx.x;
    if (idx >= NB * RR) return;
    int r = idx % RR;
    const double* l = loc64 + (size_t)idx * 4;
    double a0 = (double)anchor[(size_t)r * 4 + 0];
    double a1 = (double)anchor[(size_t)r * 4 + 1];
    double a2 = (double)anchor[(size_t)r * 4 + 2];
    double a3 = (double)anchor[(size_t)r * 4 + 3];
    double ah = a2 - a0, aw = a3 - a1;
    double acy = a0 + 0.5 * ah, acx = a1 + 0.5 * aw;
    double cy = l[0] * ah + acy, cx = l[1] * aw + acx;
    double h = exp(l[2]) * ah, w = exp(l[3]) * aw;
    double imh = (double)imh_p[0], imw = (double)imw_p[0];
    double y1 = fmin(fmax(cy - 0.5 * h, 0.0), imh);
    double x1 = fmin(fmax(cx - 0.5 * w, 0.0), imw);
    double y2 = fmin(fmax(cy + 0.5 * h, 0.0), imh);
    double x2 = fmin(fmax(cx + 0.5 * w, 0.0), imw);
    bool valid = ((y2 - y1) >= 16.0) && ((x2 - x1) >= 16.0);
    double* b = boxes + (size_t)idx * 4;
    b[0] = y1; b[1] = x1; b[2] = y2; b[3] = x2;
    double s0 = score64[(size_t)idx * 2];
    double s1 = score64[(size_t)idx * 2 + 1];
    double m = fmax(s0, s1);
    double e0 = exp(s0 - m), e1 = exp(s1 - m);
    double sc = valid ? (e1 / (e0 + e1)) : -__builtin_inf();
    u64 bits = (u64)__double_as_longlong(sc);
    u64 t = (bits >> 63) ? ~bits : (bits | 0x8000000000000000ull);
    keys[idx] = (t & 0xFFFFFFFFFFFF8000ull) | (u64)(32767 - r);
}

// ---------------- top-6000 select + full sort (per batch) ----------------
__global__ __launch_bounds__(1024) void select_kernel(
    const u64* __restrict__ keys, const double* __restrict__ boxes,
    double* __restrict__ sbox, int* __restrict__ sval) {
    __shared__ unsigned int hist[256];
    __shared__ u64 cand[8192];
    __shared__ unsigned int s_sel, s_base, s_cnt;
    int n = blockIdx.x;
    int tid = threadIdx.x;
    const u64* k = keys + (size_t)n * RR;

    u64 prefix = 0;
    unsigned int base = 0;
    for (int round = 0; round < 3; ++round) {
        if (tid < 256) hist[tid] = 0;
        __syncthreads();
        int shift_match = 64 - 8 * round;
        int shift_bin = 56 - 8 * round;
        for (int r = tid; r < RR; r += 1024) {
            u64 kv = k[r];
            bool match = (round == 0) || ((kv >> shift_match) == prefix);
            if (match) atomicAdd(&hist[(unsigned int)((kv >> shift_bin) & 0xFF)], 1u);
        }
        __syncthreads();
        if (tid == 0) {
            unsigned int c = base;
            int sel = 0;
            for (int v = 255; v >= 0; --v) {
                if (c + hist[v] >= PB) { sel = v; break; }
                c += hist[v];
            }
            s_sel = (unsigned int)sel;
            s_base = c;
        }
        __syncthreads();
        prefix = (prefix << 8) | (u64)s_sel;
        base = s_base;
        __syncthreads();
    }

    if (tid == 0) s_cnt = 0;
    __syncthreads();
    for (int r = tid; r < RR; r += 1024) {
        u64 kv = k[r];
        if ((kv >> 40) >= prefix) {
            unsigned int pos = atomicAdd(&s_cnt, 1u);
            if (pos < 8192u) cand[pos] = kv;
        }
    }
    __syncthreads();
    unsigned int cnt = s_cnt;
    if (cnt > 8192u) cnt = 8192u;
    for (unsigned int i = cnt + tid; i < 8192u; i += 1024u) cand[i] = 0ull;
    __syncthreads();

    for (unsigned int kk = 2; kk <= 8192; kk <<= 1) {
        for (unsigned int j = kk >> 1; j > 0; j >>= 1) {
            for (unsigned int t = tid; t < 4096; t += 1024) {
                unsigned int i = ((t & ~(j - 1)) << 1) | (t & (j - 1));
                unsigned int l = i | j;
                u64 a = cand[i], b = cand[l];
                bool desc = ((i & kk) == 0);
                if ((a < b) == desc) { cand[i] = b; cand[l] = a; }
            }
            __syncthreads();
        }
    }

    for (int s = tid; s < PB; s += 1024) {
        u64 kv = cand[s];
        int valid = (int)(kv >> 63);
        double b0 = 0.0, b1 = 0.0, b2 = 0.0, b3 = 0.0;
        if (valid) {
            int r = 32767 - (int)(kv & 0x7FFFull);
            const double* bp = boxes + ((size_t)n * RR + r) * 4;
            b0 = bp[0]; b1 = bp[1]; b2 = bp[2]; b3 = bp[3];
        }
        double* sp = sbox + ((size_t)n * PB + s) * 4;
        sp[0] = b0; sp[1] = b1; sp[2] = b2; sp[3] = b3;
        sval[n * PB + s] = valid;
    }
}

// ---------------- greedy NMS (R5 version: serial scan, early-exit) ----------------
__global__ __launch_bounds__(1024) void nms_kernel_f64(
    const double* __restrict__ sbox, const int* __restrict__ sval,
    float* __restrict__ rois, float* __restrict__ rind) {
    __shared__ unsigned int keepw[188];
    __shared__ double bi[4];
    int n = blockIdx.x;
    int tid = threadIdx.x;

    double by1[6], bx1[6], by2[6], bx2[6];
    bool kp[6];
    if (tid < 188) keepw[tid] = 0u;
    __syncthreads();
    #pragma unroll
    for (int c = 0; c < 6; ++c) {
        int j = tid + c * 1024;
        bool v = false;
        double a0 = 0, a1 = 0, a2 = 0, a3 = 0;
        if (j < PB) {
            const double* bp = sbox + ((size_t)n * PB + j) * 4;
            a0 = bp[0]; a1 = bp[1]; a2 = bp[2]; a3 = bp[3];
            v = sval[n * PB + j] != 0;
        }
        by1[c] = a0; bx1[c] = a1; by2[c] = a2; bx2[c] = a3;
        kp[c] = v;
        if (v) atomicOr(&keepw[j >> 5], 1u << (j & 31));
    }
    __syncthreads();

    int kc = 0;
    for (int i = 0; i < PB; ++i) {
        bool ki = (keepw[i >> 5] >> (i & 31)) & 1u;
        if (!ki) continue;
        int owner = i & 1023;
        int slot = i >> 10;
        if (tid == owner) {
            float* rp = rois + ((size_t)n * PA + kc) * 4;
            rp[0] = (float)by1[slot]; rp[1] = (float)bx1[slot];
            rp[2] = (float)by2[slot]; rp[3] = (float)bx2[slot];
            bi[0] = by1[slot]; bi[1] = bx1[slot]; bi[2] = by2[slot]; bi[3] = bx2[slot];
        }
        ++kc;
        if (kc >= PA) break;
        __syncthreads();
        double yi1 = bi[0], xi1 = bi[1], yi2 = bi[2], xi2 = bi[3];
        double ai = (yi2 - yi1) * (xi2 - xi1);
        #pragma unroll
        for (int c = 0; c < 6; ++c) {
            int j = tid + c * 1024;
            if (j > i && kp[c]) {
                double ty = fmax(yi1, by1[c]);
                double tx = fmax(xi1, bx1[c]);
                double byy = fmin(yi2, by2[c]);
                double bxx = fmin(xi2, bx2[c]);
                double ih = fmax(byy - ty, 0.0);
                double iw = fmax(bxx - tx, 0.0);
                double inter = ih * iw;
                double aj = (by2[c] - by1[c]) * (bx2[c] - bx1[c]);
                double iou = inter / (ai + aj - inter + 1e-9);
                if (iou > 0.7) {
                    kp[c] = false;
                    atomicAnd(&keepw[j >> 5], ~(1u << (j & 31)));
                }
            }
        }
        __syncthreads();
    }
    __syncthreads();

    for (int p = kc + tid; p < PA; p += 1024) {
        float* rp = rois + ((size_t)n * PA + p) * 4;
        rp[0] = 0.f; rp[1] = 0.f; rp[2] = 0.f; rp[3] = 0.f;
    }
    for (int p = tid; p < PA; p += 1024)
        rind[n * PA + p] = (float)n;
}

// ---------------- launch ----------------
extern "C" void kernel_launch(void* const* d_in, const int* in_sizes, int n_in,
                              void* d_out, int out_size, void* d_ws, size_t ws_size,
                              hipStream_t stream) {
    const float* x = (const float*)d_in[0];
    const float* w1 = (const float*)d_in[1];
    const float* b1 = (const float*)d_in[2];
    const float* w_score = (const float*)d_in[3];
    const float* b_score = (const float*)d_in[4];
    const float* w_loc = (const float*)d_in[5];
    const float* b_loc = (const float*)d_in[6];
    const int* img_h = (const int*)d_in[7];
    const int* img_w = (const int*)d_in[8];

    float* out = (float*)d_out;
    float* out_loc = out;
    float* out_score = out + 360000;
    float* out_rois = out + 540000;
    float* out_rind = out + 544800;
    float* out_anchor = out + 546000;

    const size_t interB = (size_t)NB * CMID * NPIX * 8;     // 40,960,000
    const size_t partB = 2 * interB;                        // 81,920,000
    const size_t interB_serial = (size_t)CMID * NPIX * 8;   // 10,240,000
    const size_t restB = 2880000 + 1440000 + 2880000 + 720000 + 768000 + 96000;

    int mode;                  // 2 = split-K, 1 = batched v3, 0 = serial v3
    size_t convB;
    if (ws_size >= partB + restB) { mode = 2; convB = partB; }
    else if (ws_size >= interB + restB) { mode = 1; convB = interB; }
    else { mode = 0; convB = interB_serial; }

    char* p = (char*)d_ws;
    double* conv_buf = (double*)p; p += convB;   // mode2: part[2][...]; inter aliases part[0]
    double* loc64   = (double*)p; p += 2880000;
    double* score64 = (double*)p; p += 1440000;
    double* boxes64 = (double*)p; p += 2880000;
    u64*    keys    = (u64*)p;    p += 720000;
    double* sbox64  = (double*)p; p += 768000;
    int*    sval    = (int*)p;

    hipLaunchKernelGGL(anchor_kernel, dim3(88), dim3(256), 0, stream, out_anchor);

    if (mode == 2) {
        hipLaunchKernelGGL(conv3_f64_v6, dim3(49, 8, NB), dim3(256), 0, stream,
                           x, w1, conv_buf);
        hipLaunchKernelGGL(reduce_bias_relu, dim3(20000), dim3(256), 0, stream,
                           conv_buf, b1, conv_buf);
        hipLaunchKernelGGL(heads_kernel_f64, dim3(40, NB), dim3(128), 0, stream,
                           conv_buf, w_loc, b_loc, w_score, b_score,
                           loc64, score64, out_loc, out_score, 0);
    } else if (mode == 1) {
        hipLaunchKernelGGL(conv3_f64_v3, dim3(49, 8, NB), dim3(256), 0, stream,
                           x, w1, b1, conv_buf, 0);
        hipLaunchKernelGGL(heads_kernel_f64, dim3(40, NB), dim3(128), 0, stream,
                           conv_buf, w_loc, b_loc, w_score, b_score,
                           loc64, score64, out_loc, out_score, 0);
    } else {
        for (int n = 0; n < NB; ++n) {
            hipLaunchKernelGGL(conv3_f64_v3, dim3(49, 8, 1), dim3(256), 0, stream,
                               x, w1, b1, conv_buf, n);
            hipLaunchKernelGGL(heads_kernel_f64, dim3(40, 1), dim3(128), 0, stream,
                               conv_buf, w_loc, b_loc, w_score, b_score,
                               loc64, score64, out_loc, out_score, n);
        }
    }

    hipLaunchKernelGGL(box_kernel_f64, dim3((NB * RR + 255) / 256), dim3(256), 0, stream,
                       loc64, score64, out_anchor, img_h, img_w, boxes64, keys);
    hipLaunchKernelGGL(select_kernel, dim3(4), dim3(1024), 0, stream, keys, boxes64, sbox64, sval);
    hipLaunchKernelGGL(nms_kernel_f64, dim3(4), dim3(1024), 0, stream, sbox64, sval, out_rois, out_rind);
}